// Round 8
// baseline (977.880 us; speedup 1.0000x reference)
//
#include <hip/hip_runtime.h>
#include <hip/hip_bf16.h>
#include <math.h>

#define D_MODEL 384
#define D_STATE 64
#define D_INNER 768
#define HEADDIM 96
#define NHEADS 8
#define CONV_DIM 896
#define D_IN_PROJ 1672
#define ZXB_LD 1664        /* bf16 zx row stride (z,X,B,C); dt split to fp32 */
#define BATCH 8
#define SEQ 1024
#define ROWS (BATCH*SEQ)   /* 8192 */
#define NUM_LAYERS 6
#define NC 32              /* chunks */
#define CHUNK 32           /* timesteps per chunk */
#define NPAD_IN 1792       /* 14 * 128 */
#define NPAD_OUT 384       /* 3 * 128  */
#define VP 776             /* padded Vsh row (shorts) */

typedef __hip_bfloat16 bf16;
using bf16x8_t = __attribute__((ext_vector_type(8))) short;
using f32x4_t  = __attribute__((ext_vector_type(4))) float;

__device__ __forceinline__ float softplus_f(float v){
  return v > 20.f ? v : log1pf(expf(v));
}
__device__ __forceinline__ float silu_f(float v){
  return v / (1.f + expf(-v));
}
__device__ __forceinline__ float bits_to_f(unsigned short u){
  union{unsigned u32; float f;} cv; cv.u32 = ((unsigned)u)<<16; return cv.f;
}
__device__ __forceinline__ unsigned short f_to_bits(float f){
  union{bf16 b; unsigned short u;} cv; cv.b = __float2bfloat16(f); return cv.u;
}

/* ------- weight transpose + fp32->bf16, all layers batched via grid.z ---------- */
__global__ void wconv_kernel(const float* __restrict__ W, bf16* __restrict__ Wt,
                             int K, int N, int Npad){
  __shared__ float tile[32][33];
  W  += (size_t)blockIdx.z*K*N;
  Wt += (size_t)blockIdx.z*Npad*K;
  int kb = blockIdx.y*32, nb = blockIdx.x*32;
  int tx = threadIdx.x, ty = threadIdx.y;   /* 32 x 8 */
  #pragma unroll
  for (int r=0;r<32;r+=8){
    int k = kb+ty+r, n = nb+tx;
    tile[ty+r][tx] = (k<K && n<N) ? W[(size_t)k*N+n] : 0.f;
  }
  __syncthreads();
  #pragma unroll
  for (int r=0;r<32;r+=8){
    int n = nb+ty+r, k = kb+tx;
    if (n<Npad && k<K) Wt[(size_t)n*K+k] = __float2bfloat16(tile[tx][ty+r]);
  }
}

/* ------- bf16 MFMA GEMM ---------------------------------------------------------
   MODE 0: A bf16, out fp32 +=   (out-projection)
   MODE 1: A = fp32 `out` with fused LayerNorm -> bf16; writes zxb + dtraw.      */
template<int MODE>
__global__ __launch_bounds__(256) void mfma_gemm(
    const unsigned short* __restrict__ Ab,  /* MODE0: M x K bf16 row-major */
    const float* __restrict__ Af,           /* MODE1: M x 384 fp32 (pre-LN) */
    const float* __restrict__ lnw, const float* __restrict__ lnb,
    const unsigned short* __restrict__ Bt,  /* Npad x K bf16 (B transposed) */
    float* __restrict__ Cf,                 /* MODE0: M x ldc fp32 (accum) */
    unsigned short* __restrict__ Cbf,       /* MODE1: M x ZXB_LD bf16 */
    float* __restrict__ dtraw,              /* MODE1: M x 8 fp32 */
    int N, int K, int ldc){
  __shared__ __align__(16) unsigned short smem[128*136];  /* 34 KB */
  __shared__ float musm[128], rssm[128], lnwb[768];
  unsigned short* As = smem;          /* 128*32 */
  unsigned short* Bs = smem + 4096;   /* 128*32 */
  const int tid = threadIdx.x;
  const int wave = tid >> 6, lane = tid & 63;
  const int lq = lane >> 4, lm = lane & 15;
  const int m0 = blockIdx.y * 128, n0 = blockIdx.x * 128;
  const int wm = (wave >> 1) * 64, wn = (wave & 1) * 64;

  if (MODE == 1){
    /* LN stats pre-pass: 2 threads per row, pair-reduce via shuffle */
    for (int i=tid; i<384; i+=256){ lnwb[i]=lnw[i]; lnwb[384+i]=lnb[i]; }
    int row = tid >> 1;
    const float4* xr = (const float4*)(Af + (size_t)(m0+row)*D_MODEL + (tid&1)*192);
    float s=0.f, sq=0.f;
    for (int k=0;k<48;k++){
      float4 v = xr[k];
      s += (v.x+v.y)+(v.z+v.w);
      sq += (v.x*v.x+v.y*v.y)+(v.z*v.z+v.w*v.w);
    }
    s  += __shfl_xor(s,1);
    sq += __shfl_xor(sq,1);
    if ((tid & 1) == 0){
      float mu = s*(1.f/D_MODEL);
      float var = sq*(1.f/D_MODEL) - mu*mu;
      var = var < 0.f ? 0.f : var;
      musm[row] = mu;
      rssm[row] = rsqrtf(var + 1e-12f);
    }
    __syncthreads();
  }

  f32x4_t acc[4][4];
  #pragma unroll
  for (int i=0;i<4;i++)
    #pragma unroll
    for (int j=0;j<4;j++)
      acc[i][j] = (f32x4_t){0.f,0.f,0.f,0.f};

  for (int k0 = 0; k0 < K; k0 += 32){
    if (k0) __syncthreads();
    if (MODE == 0){
      #pragma unroll
      for (int q=0;q<2;q++){
        int o = q*4096 + wave*1024 + lane*16;
        int m = o >> 6;
        int kb = o & 63;
        const unsigned short* ga = Ab + (size_t)(m0+m)*K + k0 + (kb>>1);
        __builtin_amdgcn_global_load_lds(
            (const __attribute__((address_space(1))) void*)ga,
            (__attribute__((address_space(3))) void*)((char*)As + o), 16, 0, 0);
        const unsigned short* gb = Bt + (size_t)(n0+m)*K + k0 + (kb>>1);
        __builtin_amdgcn_global_load_lds(
            (const __attribute__((address_space(1))) void*)gb,
            (__attribute__((address_space(3))) void*)((char*)Bs + o), 16, 0, 0);
      }
    } else {
      /* B via global_load_lds */
      #pragma unroll
      for (int q=0;q<2;q++){
        int o = q*4096 + wave*1024 + lane*16;
        int m = o >> 6;
        int kb = o & 63;
        const unsigned short* gb = Bt + (size_t)(n0+m)*K + k0 + (kb>>1);
        __builtin_amdgcn_global_load_lds(
            (const __attribute__((address_space(1))) void*)gb,
            (__attribute__((address_space(3))) void*)((char*)Bs + o), 16, 0, 0);
      }
      /* A: fp32 load -> LN -> bf16 -> LDS (16 cols per thread, one row) */
      {
        int row = tid >> 1;
        int cb2 = (tid & 1) * 16;
        const float4* ap = (const float4*)(Af + (size_t)(m0+row)*D_MODEL + k0 + cb2);
        float4 v0 = ap[0], v1 = ap[1], v2 = ap[2], v3 = ap[3];
        float mu = musm[row], rs = rssm[row];
        bf16x8_t h0, h1;
        const float* wv = lnwb + k0 + cb2;
        const float* bv = lnwb + 384 + k0 + cb2;
        float tv[16] = {v0.x,v0.y,v0.z,v0.w, v1.x,v1.y,v1.z,v1.w,
                        v2.x,v2.y,v2.z,v2.w, v3.x,v3.y,v3.z,v3.w};
        #pragma unroll
        for (int j=0;j<8;j++)  h0[j] = (short)f_to_bits((tv[j]-mu)*rs*wv[j] + bv[j]);
        #pragma unroll
        for (int j=0;j<8;j++)  h1[j] = (short)f_to_bits((tv[8+j]-mu)*rs*wv[8+j] + bv[8+j]);
        *(bf16x8_t*)(As + row*32 + cb2)     = h0;
        *(bf16x8_t*)(As + row*32 + cb2 + 8) = h1;
      }
    }
    __syncthreads();
    bf16x8_t af[4], bfv[4];
    #pragma unroll
    for (int i=0;i<4;i++)
      af[i]  = *(const bf16x8_t*)(As + (wm + i*16 + lm)*32 + lq*8);
    #pragma unroll
    for (int j=0;j<4;j++)
      bfv[j] = *(const bf16x8_t*)(Bs + (wn + j*16 + lm)*32 + lq*8);
    #pragma unroll
    for (int i=0;i<4;i++)
      #pragma unroll
      for (int j=0;j<4;j++)
        acc[i][j] = __builtin_amdgcn_mfma_f32_16x16x32_bf16(af[i], bfv[j], acc[i][j], 0, 0, 0);
  }

  if (MODE == 1){
    if (n0 == ZXB_LD){
      /* dt block: local cols 0..7 are dt (fp32 direct); rest padding */
      if ((wave & 1) == 0 && lm < 8){
        #pragma unroll
        for (int i=0;i<4;i++){
          int row = m0 + wm + i*16 + lq*4;
          #pragma unroll
          for (int r=0;r<4;r++)
            dtraw[(size_t)(row+r)*8 + lm] = acc[i][0][r];
        }
      }
      return;
    }
    __syncthreads();   /* done reading As/Bs: reuse smem as C-stage */
    #pragma unroll
    for (int i=0;i<4;i++){
      int rl = wm + i*16 + lq*4;
      #pragma unroll
      for (int j=0;j<4;j++){
        int cl = wn + j*16 + lm;
        #pragma unroll
        for (int r=0;r<4;r++)
          smem[(rl+r)*136 + cl] = f_to_bits(acc[i][j][r]);
      }
    }
    __syncthreads();
    {
      int row = tid >> 1;
      int cbase = (tid & 1) * 64;
      size_t gb = (size_t)(m0 + row) * ZXB_LD + n0 + cbase;
      #pragma unroll
      for (int k=0;k<8;k++)
        *(bf16x8_t*)(Cbf + gb + k*8) = *(const bf16x8_t*)&smem[row*136 + cbase + k*8];
    }
  } else {
    float* smf = (float*)smem;   /* 64 x 132 fp32 */
    #pragma unroll
    for (int h=0;h<2;h++){
      __syncthreads();
      if ((wave >> 1) == h){
        #pragma unroll
        for (int i=0;i<4;i++){
          int rl = i*16 + lq*4;
          #pragma unroll
          for (int j=0;j<4;j++){
            int cl = wn + j*16 + lm;
            #pragma unroll
            for (int r=0;r<4;r++)
              smf[(rl+r)*132 + cl] = acc[i][j][r];
          }
        }
      }
      __syncthreads();
      int row = tid >> 2;
      int cbase = (tid & 3) * 32;
      float* gp = Cf + (size_t)(m0 + h*64 + row)*ldc + n0 + cbase;
      #pragma unroll
      for (int k=0;k<8;k++){
        float4 v = *(float4*)(gp + k*4);
        float4 a = *(const float4*)&smf[row*132 + cbase + k*4];
        v.x+=a.x; v.y+=a.y; v.z+=a.z; v.w+=a.w;
        *(float4*)(gp + k*4) = v;
      }
    }
  }
}

/* ==== fused conv(k=4)+silu + dt/softplus + cumsum + chunked-SSD matmuls ======== */
__global__ __launch_bounds__(256) void fused_scan_kernel(
    const unsigned short* __restrict__ zxb, const float* __restrict__ dtraw,
    const float* __restrict__ cw, const float* __restrict__ cb,
    const float* __restrict__ dt_bias, const float* __restrict__ A_log,
    const float* __restrict__ D_skip,
    float* __restrict__ cumb, float* __restrict__ Dc,
    unsigned short* __restrict__ Cb, unsigned short* __restrict__ Sb,
    unsigned short* __restrict__ y){
  __shared__ __align__(16) unsigned short XshT[192*40];  /* X^T[p_local][t] */
  __shared__ __align__(16) unsigned short BshT[64*40];   /* B^T[n][t] */
  __shared__ __align__(16) unsigned short Bsh[32*72];    /* B[t][n] */
  __shared__ __align__(16) unsigned short Csh[32*72];    /* C[t][n] */
  __shared__ __align__(16) unsigned short Msh[2*32*40];  /* M~ per head */
  __shared__ float dtsh[64], Lsh[64], wsh[64];
  const int tid = threadIdx.x;
  const int bid = blockIdx.x;
  const int hp = bid & 3, c = (bid >> 2) & 31, b = bid >> 7;
  const int h_base = hp*2;
  const int t0 = c*CHUNK;

  if (tid < 64){
    int hi = tid >> 5, t = tid & 31;
    int hg = h_base + hi;
    float raw = dtraw[(size_t)(b*SEQ + t0 + t)*8 + hg];
    float dtv_ = softplus_f(raw + dt_bias[hg]);
    dtsh[tid] = dtv_;
    Lsh[tid]  = dtv_ * (-expf(A_log[hg]));
  }

  #pragma unroll
  for (int it=0; it<2; it++){
    int ci = it*256 + tid;
    if (ci < 320){
      int gcol;
      if (ci < 192) gcol = D_INNER + (h_base + ci/96)*HEADDIM + (ci%96);
      else          gcol = D_INNER + D_INNER + (ci - 192);
      int cch = gcol - D_INNER;
      float4 w4 = *(const float4*)(cw + cch*4);
      float bias = cb[cch];
      const unsigned short* src = zxb + (size_t)b*SEQ*ZXB_LD + gcol;
      float v0=0.f,v1=0.f,v2=0.f,v3=0.f;
      unsigned prev = 0;
      for (int t=-3; t<32; t++){
        int l = t0 + t;
        float nv = (l >= 0) ? bits_to_f(src[(size_t)l*ZXB_LD]) : 0.f;
        v0=v1; v1=v2; v2=v3; v3=nv;
        if (t < 0) continue;
        float a = silu_f(bias + w4.x*v0 + w4.y*v1 + w4.z*v2 + w4.w*v3);
        unsigned short ub = f_to_bits(a);
        if (ci < 192){
          if (t & 1) *(unsigned*)&XshT[ci*40 + (t-1)] = prev | ((unsigned)ub<<16);
          else prev = ub;
        } else if (cch < CONV_DIM - D_STATE){
          int n = cch - D_INNER;
          Bsh[t*72 + n] = ub;
          if (t & 1) *(unsigned*)&BshT[n*40 + (t-1)] = prev | ((unsigned)ub<<16);
          else prev = ub;
        } else {
          Csh[t*72 + (cch - D_INNER - D_STATE)] = ub;
        }
      }
    }
  }
  __syncthreads();

  if (tid < 2){
    int hg = h_base + tid;
    float L = 0.f;
    float* cbp = cumb + ((size_t)((b*NC + c)*NHEADS) + hg)*CHUNK;
    for (int t=0;t<32;t++){
      L += Lsh[tid*32+t];
      Lsh[tid*32+t] = L;
      cbp[t] = __expf(L);
    }
    Dc[(b*NHEADS + hg)*NC + c] = __expf(L);
    for (int t=0;t<32;t++)
      wsh[tid*32+t] = __expf(L - Lsh[tid*32+t]) * dtsh[tid*32+t];
  }
  __syncthreads();

  const int wave = tid >> 6, lane = tid & 63;
  const int lq = lane >> 4, lm = lane & 15;
  const f32x4_t zero = (f32x4_t){0.f,0.f,0.f,0.f};

  if (wave < 2){
    f32x4_t G[2][2];
    #pragma unroll
    for (int i=0;i<2;i++){ G[i][0]=zero; G[i][1]=zero; }
    #pragma unroll
    for (int kt=0; kt<2; kt++){
      bf16x8_t ca[2], bb[2];
      #pragma unroll
      for (int ti=0;ti<2;ti++)
        ca[ti] = *(const bf16x8_t*)&Csh[(lm+ti*16)*72 + kt*32 + lq*8];
      #pragma unroll
      for (int si=0;si<2;si++)
        bb[si] = *(const bf16x8_t*)&Bsh[(lm+si*16)*72 + kt*32 + lq*8];
      #pragma unroll
      for (int ti=0;ti<2;ti++)
        #pragma unroll
        for (int si=0;si<2;si++)
          G[ti][si] = __builtin_amdgcn_mfma_f32_16x16x32_bf16(ca[ti], bb[si], G[ti][si], 0,0,0);
    }
    int hi = wave;
    float Dk = D_skip[h_base + hi];
    float Lss[2], dts[2];
    #pragma unroll
    for (int si=0;si<2;si++){ Lss[si]=Lsh[hi*32+si*16+lm]; dts[si]=dtsh[hi*32+si*16+lm]; }
    #pragma unroll
    for (int ti=0;ti<2;ti++){
      #pragma unroll
      for (int r=0;r<4;r++){
        int t = ti*16 + lq*4 + r;
        float Lt = Lsh[hi*32 + t];
        #pragma unroll
        for (int si=0;si<2;si++){
          int s = si*16 + lm;
          float m = 0.f;
          if (s <= t){
            m = G[ti][si][r]*__expf(Lt - Lss[si])*dts[si];
            if (s == t) m += Dk;
          }
          Msh[hi*1280 + t*40 + s] = f_to_bits(m);
        }
      }
    }
  } else if (hp == 0){
    int lt = tid - 128;
    for (int i = lt; i < 512; i += 128){
      int t = i >> 4, q = i & 15;
      *(ushort4*)(Cb + ((size_t)(b*SEQ) + t0 + t)*D_STATE + q*4) =
          *(const ushort4*)&Csh[t*72 + q*4];
    }
  }
  __syncthreads();

  {
    int hi = wave & 1, hg = h_base + hi;
    int ptb = (wave >> 1)*3;
    bf16x8_t mf[2];
    #pragma unroll
    for (int tt=0;tt<2;tt++)
      mf[tt] = *(const bf16x8_t*)&Msh[hi*1280 + (lm+tt*16)*40 + lq*8];
    float wv[8];
    #pragma unroll
    for (int j=0;j<8;j++) wv[j] = wsh[hi*32 + lq*8 + j];
    bf16x8_t bw[4];
    #pragma unroll
    for (int nt=0;nt<4;nt++){
      bf16x8_t raw = *(const bf16x8_t*)&BshT[(lm+nt*16)*40 + lq*8];
      #pragma unroll
      for (int j=0;j<8;j++)
        bw[nt][j] = (short)f_to_bits(bits_to_f((unsigned short)raw[j]) * wv[j]);
    }
    const size_t sbase = ((size_t)((b*NC + c)*NHEADS) + hg)*HEADDIM*D_STATE;
    #pragma unroll
    for (int pp=0; pp<3; pp++){
      int pt = ptb + pp;
      bf16x8_t xf = *(const bf16x8_t*)&XshT[(hi*96 + pt*16 + lm)*40 + lq*8];
      #pragma unroll
      for (int tt=0;tt<2;tt++){
        f32x4_t a = __builtin_amdgcn_mfma_f32_16x16x32_bf16(mf[tt], xf, zero, 0,0,0);
        #pragma unroll
        for (int r=0;r<4;r++){
          int t = tt*16 + lq*4 + r;
          y[((size_t)(b*SEQ) + t0 + t)*D_INNER + hg*HEADDIM + pt*16 + lm] = f_to_bits(a[r]);
        }
      }
      #pragma unroll
      for (int nt=0;nt<4;nt++){
        f32x4_t s = __builtin_amdgcn_mfma_f32_16x16x32_bf16(xf, bw[nt], zero, 0,0,0);
        #pragma unroll
        for (int r=0;r<4;r++){
          int p = pt*16 + lq*4 + r;
          Sb[sbase + (size_t)p*D_STATE + nt*16 + lm] = f_to_bits(s[r]);
        }
      }
    }
  }
}

/* ---- sequential chunk combine on bf16 S (in-place -> Hin) --------------------- */
__global__ __launch_bounds__(256) void combine_kernel(
    unsigned short* __restrict__ S, const float* __restrict__ Dc){
  int g = blockIdx.x*256 + threadIdx.x;     /* (b,h,p,nq): 8*8*96*16 = 98304 */
  int nq = g & 15;
  int p  = (g >> 4) % 96;
  int h  = (g / (16*96)) & 7;
  int b  = g / (16*96*8);
  const float* Dp = Dc + (size_t)(b*NHEADS + h)*NC;
  float H0=0.f,H1=0.f,H2=0.f,H3=0.f;
  for (int c=0;c<NC;c++){
    size_t base = ((((size_t)(b*NC + c)*NHEADS + h)*HEADDIM + p)*D_STATE + nq*4);
    ushort4 s = *(ushort4*)(S + base);
    float s0=bits_to_f(s.x), s1=bits_to_f(s.y), s2=bits_to_f(s.z), s3=bits_to_f(s.w);
    *(ushort4*)(S + base) = make_ushort4(f_to_bits(H0),f_to_bits(H1),f_to_bits(H2),f_to_bits(H3));
    float D = Dp[c];
    H0 = fmaf(D,H0,s0); H1 = fmaf(D,H1,s1); H2 = fmaf(D,H2,s2); H3 = fmaf(D,H3,s3);
  }
}

/* ==== fused: y + cum*(C@Hin^T); gate silu(z); RMSNorm -> ygb (16-row blocks) === */
__global__ __launch_bounds__(256) void hinfuse_kernel(
    const unsigned short* __restrict__ Cb, const unsigned short* __restrict__ Hinb,
    const float* __restrict__ cumb, const unsigned short* __restrict__ zxb,
    const float* __restrict__ nw, const unsigned short* __restrict__ ybuf,
    unsigned short* __restrict__ ygb){
  __shared__ __align__(16) unsigned short Vsh[16*VP];
  __shared__ float cumsh[128];    /* [h][tl] for this 16-row half */
  __shared__ float rowsq[16];
  const int tid = threadIdx.x;
  const int half = blockIdx.x & 1;
  const int c = (blockIdx.x >> 1) & 31, b = blockIdx.x >> 6;
  const int t0 = c*CHUNK + half*16;
  if (tid < 128)
    cumsh[tid] = cumb[((size_t)((b*NC + c)*NHEADS) + (tid>>4))*CHUNK + half*16 + (tid&15)];
  if (tid < 16) rowsq[tid] = 0.f;
  __syncthreads();
  const int wave = tid >> 6, lane = tid & 63;
  const int lq = lane >> 4, lm = lane & 15;
  const f32x4_t zero = (f32x4_t){0.f,0.f,0.f,0.f};
  float sql[4] = {};
  for (int hh=0; hh<2; hh++){
    int h = wave*2 + hh;
    const unsigned short* Hb = Hinb + ((size_t)((b*NC + c)*NHEADS) + h)*HEADDIM*D_STATE;
    bf16x8_t ca[2];
    #pragma unroll
    for (int kt=0;kt<2;kt++)
      ca[kt] = *(const bf16x8_t*)(Cb +
          ((size_t)(b*SEQ) + t0 + lm)*D_STATE + kt*32 + lq*8);
    #pragma unroll
    for (int pt=0; pt<6; pt++){
      bf16x8_t hf0 = *(const bf16x8_t*)&Hb[(size_t)(lm+pt*16)*D_STATE + lq*8];
      bf16x8_t hf1 = *(const bf16x8_t*)&Hb[(size_t)(lm+pt*16)*D_STATE + 32 + lq*8];
      f32x4_t acc;
      acc = __builtin_amdgcn_mfma_f32_16x16x32_bf16(ca[0], hf0, zero, 0,0,0);
      acc = __builtin_amdgcn_mfma_f32_16x16x32_bf16(ca[1], hf1, acc, 0,0,0);
      int pcol = h*HEADDIM + pt*16 + lm;
      #pragma unroll
      for (int r=0;r<4;r++){
        int t = lq*4 + r;
        size_t row = (size_t)(b*SEQ) + t0 + t;
        float yv = bits_to_f(ybuf[row*D_INNER + pcol]) + cumsh[h*16+t]*acc[r];
        float z  = bits_to_f(zxb[row*ZXB_LD + pcol]);
        float v  = yv * silu_f(z);
        Vsh[t*VP + pcol] = f_to_bits(v);
        sql[r] += v*v;
      }
    }
  }
  #pragma unroll
  for (int r=0;r<4;r++){
    float v = sql[r];
    v += __shfl_xor(v,1); v += __shfl_xor(v,2);
    v += __shfl_xor(v,4); v += __shfl_xor(v,8);
    if (lm == 0) atomicAdd(&rowsq[lq*4 + r], v);
  }
  __syncthreads();
  if (tid < 16) rowsq[tid] = rsqrtf(rowsq[tid]*(1.f/D_INNER) + 1e-5f);
  __syncthreads();
  for (int i=tid; i<16*192; i+=256){
    int t = i/192, q = i%192;
    ushort4 pv = *(const ushort4*)&Vsh[t*VP + q*4];
    float rms = rowsq[t];
    float4 w4 = *(const float4*)(nw + q*4);
    ushort4 o;
    o.x = f_to_bits(bits_to_f(pv.x)*rms*w4.x);
    o.y = f_to_bits(bits_to_f(pv.y)*rms*w4.y);
    o.z = f_to_bits(bits_to_f(pv.z)*rms*w4.z);
    o.w = f_to_bits(bits_to_f(pv.w)*rms*w4.w);
    *(ushort4*)(ygb + ((size_t)(b*SEQ) + t0 + t)*D_INNER + q*4) = o;
  }
}

extern "C" void kernel_launch(void* const* d_in, const int* in_sizes, int n_in,
                              void* d_out, int out_size, void* d_ws, size_t ws_size,
                              hipStream_t stream){
  const float* x0      = (const float*)d_in[0];
  const float* ln_w    = (const float*)d_in[1];
  const float* ln_b    = (const float*)d_in[2];
  const float* W_in    = (const float*)d_in[3];
  const float* conv_w  = (const float*)d_in[4];
  const float* conv_b  = (const float*)d_in[5];
  const float* dt_bias = (const float*)d_in[6];
  const float* A_log   = (const float*)d_in[7];
  const float* D_skip  = (const float*)d_in[8];
  const float* norm_w  = (const float*)d_in[9];
  const float* W_out   = (const float*)d_in[10];
  float* out = (float*)d_out;

  float* p    = (float*)d_ws;
  unsigned short* zxb = (unsigned short*)p;   p += (size_t)ROWS*ZXB_LD/2;
  float* dtraw = p;  p += (size_t)ROWS*8;
  float* cumb  = p;  p += (size_t)BATCH*NHEADS*SEQ;
  float* Dc    = p;  p += (size_t)BATCH*NHEADS*NC;
  unsigned short* ybuf = (unsigned short*)p;  p += (size_t)ROWS*D_INNER/2;
  unsigned short* ygb  = (unsigned short*)p;  p += (size_t)ROWS*D_INNER/2;
  unsigned short* Sb   = (unsigned short*)p;  p += (size_t)BATCH*NC*NHEADS*HEADDIM*D_STATE/2;
  unsigned short* Cb   = (unsigned short*)p;  p += (size_t)ROWS*D_STATE/2;
  bf16* Wt  = (bf16*)p; p += (size_t)NUM_LAYERS*NPAD_IN*D_MODEL/2;
  bf16* Wot = (bf16*)p;

  hipMemcpyAsync(out, x0, (size_t)ROWS*D_MODEL*sizeof(float),
                 hipMemcpyDeviceToDevice, stream);

  wconv_kernel<<<dim3(NPAD_IN/32, D_MODEL/32, NUM_LAYERS), dim3(32,8), 0, stream>>>(
      W_in, Wt, D_MODEL, D_IN_PROJ, NPAD_IN);
  wconv_kernel<<<dim3(NPAD_OUT/32, D_INNER/32, NUM_LAYERS), dim3(32,8), 0, stream>>>(
      W_out, Wot, D_INNER, D_MODEL, NPAD_OUT);

  for (int i=0;i<NUM_LAYERS;i++){
    mfma_gemm<1><<<dim3(NPAD_IN/128, ROWS/128), 256, 0, stream>>>(
        nullptr, out, ln_w+(size_t)i*D_MODEL, ln_b+(size_t)i*D_MODEL,
        (const unsigned short*)(Wt + (size_t)i*NPAD_IN*D_MODEL),
        nullptr, zxb, dtraw, D_IN_PROJ, D_MODEL, 0);
    fused_scan_kernel<<<BATCH*NC*4, 256, 0, stream>>>(
        zxb, dtraw, conv_w + (size_t)i*CONV_DIM*4, conv_b + (size_t)i*CONV_DIM,
        dt_bias+(size_t)i*NHEADS, A_log+(size_t)i*NHEADS, D_skip+(size_t)i*NHEADS,
        cumb, Dc, Cb, Sb, ybuf);
    combine_kernel<<<(BATCH*NHEADS*HEADDIM*16)/256, 256, 0, stream>>>(Sb, Dc);
    hinfuse_kernel<<<BATCH*NC*2, 256, 0, stream>>>(
        Cb, Sb, cumb, zxb, norm_w+(size_t)i*D_INNER, ybuf, ygb);
    mfma_gemm<0><<<dim3(NPAD_OUT/128, ROWS/128), 256, 0, stream>>>(
        (const unsigned short*)ygb, nullptr, nullptr, nullptr,
        (const unsigned short*)(Wot + (size_t)i*NPAD_OUT*D_INNER),
        out, nullptr, nullptr, D_MODEL, D_INNER, D_MODEL);
  }
}

// Round 9
// 850.733 us; speedup vs baseline: 1.1495x; 1.1495x over previous
//
#include <hip/hip_runtime.h>
#include <hip/hip_bf16.h>
#include <math.h>

#define D_MODEL 384
#define D_STATE 64
#define D_INNER 768
#define HEADDIM 96
#define NHEADS 8
#define CONV_DIM 896
#define D_IN_PROJ 1672
#define ZXB_LD 1664        /* bf16 zx row stride (z,X,B,C); dt split to fp32 */
#define BATCH 8
#define SEQ 1024
#define ROWS (BATCH*SEQ)   /* 8192 */
#define NUM_LAYERS 6
#define NC 32              /* chunks */
#define CHUNK 32           /* timesteps per chunk */
#define NPAD_IN 1792       /* 14 * 128 */
#define NPAD_OUT 384       /* 3 * 128  */
#define VP 776             /* padded Vsh row (shorts) */

typedef __hip_bfloat16 bf16;
using bf16x8_t = __attribute__((ext_vector_type(8))) short;
using f32x4_t  = __attribute__((ext_vector_type(4))) float;

__device__ __forceinline__ float softplus_f(float v){
  return v > 20.f ? v : log1pf(expf(v));
}
__device__ __forceinline__ float silu_f(float v){
  return v / (1.f + expf(-v));
}
__device__ __forceinline__ float bits_to_f(unsigned short u){
  union{unsigned u32; float f;} cv; cv.u32 = ((unsigned)u)<<16; return cv.f;
}
__device__ __forceinline__ unsigned short f_to_bits(float f){
  union{bf16 b; unsigned short u;} cv; cv.b = __float2bfloat16(f); return cv.u;
}

/* ------- weight transpose + fp32->bf16, all layers batched via grid.z ---------- */
__global__ void wconv_kernel(const float* __restrict__ W, bf16* __restrict__ Wt,
                             int K, int N, int Npad){
  __shared__ float tile[32][33];
  W  += (size_t)blockIdx.z*K*N;
  Wt += (size_t)blockIdx.z*Npad*K;
  int kb = blockIdx.y*32, nb = blockIdx.x*32;
  int tx = threadIdx.x, ty = threadIdx.y;   /* 32 x 8 */
  #pragma unroll
  for (int r=0;r<32;r+=8){
    int k = kb+ty+r, n = nb+tx;
    tile[ty+r][tx] = (k<K && n<N) ? W[(size_t)k*N+n] : 0.f;
  }
  __syncthreads();
  #pragma unroll
  for (int r=0;r<32;r+=8){
    int n = nb+ty+r, k = kb+tx;
    if (n<Npad && k<K) Wt[(size_t)n*K+k] = __float2bfloat16(tile[tx][ty+r]);
  }
}

/* ---------------- LayerNorm: one block (128 thr) per row of 384 -> bf16 -------- */
__global__ void ln_kernel(const float* __restrict__ x, const float* __restrict__ w,
                          const float* __restrict__ b, bf16* __restrict__ o){
  int r = blockIdx.x;
  int tid = threadIdx.x; /* 128 */
  const float* xr = x + (size_t)r*D_MODEL;
  float v[3];
  float s = 0.f, sq = 0.f;
  #pragma unroll
  for (int e=0;e<3;e++){ v[e]=xr[tid+128*e]; s+=v[e]; sq+=v[e]*v[e]; }
  __shared__ float reds[128], redq[128];
  reds[tid]=s; redq[tid]=sq; __syncthreads();
  for (int off=64; off>0; off>>=1){
    if (tid<off){ reds[tid]+=reds[tid+off]; redq[tid]+=redq[tid+off]; }
    __syncthreads();
  }
  float mu = reds[0]*(1.f/D_MODEL);
  float var = redq[0]*(1.f/D_MODEL) - mu*mu;
  var = var < 0.f ? 0.f : var;
  float rstd = rsqrtf(var + 1e-12f);
  bf16* orow = o + (size_t)r*D_MODEL;
  #pragma unroll
  for (int e=0;e<3;e++){
    int c=tid+128*e;
    orow[c] = __float2bfloat16((v[e]-mu)*rstd*w[c] + b[c]);
  }
}

/* ------- bf16 MFMA GEMM: MODE 0: fp32 += ; MODE 1: bf16 zxb + fp32 dtraw -------
   Epilogues vectorized via LDS bounce (smem reused after K-loop).              */
template<int MODE>
__global__ __launch_bounds__(256) void mfma_gemm(
    const unsigned short* __restrict__ A,   /* M x K bf16, row-major */
    const unsigned short* __restrict__ Bt,  /* Npad x K bf16 (B transposed) */
    float* __restrict__ Cf,                 /* MODE0: M x ldc fp32 (accum) */
    unsigned short* __restrict__ Cbf,       /* MODE1: M x ZXB_LD bf16 */
    float* __restrict__ dtraw,              /* MODE1: M x 8 fp32 */
    int N, int K, int ldc){
  __shared__ __align__(16) unsigned short smem[128*136];  /* 34 KB */
  unsigned short* As = smem;          /* 128*32 */
  unsigned short* Bs = smem + 4096;   /* 128*32 */
  const int tid = threadIdx.x;
  const int wave = tid >> 6, lane = tid & 63;
  const int lq = lane >> 4, lm = lane & 15;
  const int m0 = blockIdx.y * 128, n0 = blockIdx.x * 128;
  const int wm = (wave >> 1) * 64, wn = (wave & 1) * 64;
  f32x4_t acc[4][4];
  #pragma unroll
  for (int i=0;i<4;i++)
    #pragma unroll
    for (int j=0;j<4;j++)
      acc[i][j] = (f32x4_t){0.f,0.f,0.f,0.f};

  for (int k0 = 0; k0 < K; k0 += 32){
    if (k0) __syncthreads();
    #pragma unroll
    for (int q=0;q<2;q++){
      int o = q*4096 + wave*1024 + lane*16;
      int m = o >> 6;
      int kb = o & 63;
      const unsigned short* ga = A  + (size_t)(m0+m)*K + k0 + (kb>>1);
      __builtin_amdgcn_global_load_lds(
          (const __attribute__((address_space(1))) void*)ga,
          (__attribute__((address_space(3))) void*)((char*)As + o), 16, 0, 0);
      const unsigned short* gb = Bt + (size_t)(n0+m)*K + k0 + (kb>>1);
      __builtin_amdgcn_global_load_lds(
          (const __attribute__((address_space(1))) void*)gb,
          (__attribute__((address_space(3))) void*)((char*)Bs + o), 16, 0, 0);
    }
    __syncthreads();
    bf16x8_t af[4], bfv[4];
    #pragma unroll
    for (int i=0;i<4;i++)
      af[i]  = *(const bf16x8_t*)(As + (wm + i*16 + lm)*32 + lq*8);
    #pragma unroll
    for (int j=0;j<4;j++)
      bfv[j] = *(const bf16x8_t*)(Bs + (wn + j*16 + lm)*32 + lq*8);
    #pragma unroll
    for (int i=0;i<4;i++)
      #pragma unroll
      for (int j=0;j<4;j++)
        acc[i][j] = __builtin_amdgcn_mfma_f32_16x16x32_bf16(af[i], bfv[j], acc[i][j], 0, 0, 0);
  }

  if (MODE == 1){
    if (n0 == ZXB_LD){
      /* dt block: local cols 0..7 are dt (fp32 direct); rest is padding */
      if ((wave & 1) == 0 && lm < 8){
        #pragma unroll
        for (int i=0;i<4;i++){
          int row = m0 + wm + i*16 + lq*4;
          #pragma unroll
          for (int r=0;r<4;r++)
            dtraw[(size_t)(row+r)*8 + lm] = acc[i][0][r];
        }
      }
      return;
    }
    __syncthreads();   /* done reading As/Bs: reuse smem as C-stage */
    #pragma unroll
    for (int i=0;i<4;i++){
      int rl = wm + i*16 + lq*4;
      #pragma unroll
      for (int j=0;j<4;j++){
        int cl = wn + j*16 + lm;
        #pragma unroll
        for (int r=0;r<4;r++)
          smem[(rl+r)*136 + cl] = f_to_bits(acc[i][j][r]);
      }
    }
    __syncthreads();
    /* 2 threads/row, 8x 16B stores each */
    {
      int row = tid >> 1;
      int cbase = (tid & 1) * 64;
      size_t gb = (size_t)(m0 + row) * ZXB_LD + n0 + cbase;
      #pragma unroll
      for (int k=0;k<8;k++)
        *(bf16x8_t*)(Cbf + gb + k*8) = *(const bf16x8_t*)&smem[row*136 + cbase + k*8];
    }
  } else {
    /* MODE 0: accumulate into fp32 out; two 64-row halves through LDS */
    float* smf = (float*)smem;   /* 64 x 132 fp32 */
    #pragma unroll
    for (int h=0;h<2;h++){
      __syncthreads();
      if ((wave >> 1) == h){
        #pragma unroll
        for (int i=0;i<4;i++){
          int rl = i*16 + lq*4;            /* wm-relative */
          #pragma unroll
          for (int j=0;j<4;j++){
            int cl = wn + j*16 + lm;
            #pragma unroll
            for (int r=0;r<4;r++)
              smf[(rl+r)*132 + cl] = acc[i][j][r];
          }
        }
      }
      __syncthreads();
      int row = tid >> 2;
      int cbase = (tid & 3) * 32;
      float* gp = Cf + (size_t)(m0 + h*64 + row)*ldc + n0 + cbase;
      #pragma unroll
      for (int k=0;k<8;k++){
        float4 v = *(float4*)(gp + k*4);
        float4 a = *(const float4*)&smf[row*132 + cbase + k*4];
        v.x+=a.x; v.y+=a.y; v.z+=a.z; v.w+=a.w;
        *(float4*)(gp + k*4) = v;
      }
    }
  }
}

/* ==== fused conv(k=4)+silu + dt/softplus + cumsum + chunked-SSD matmuls ======== */
__global__ __launch_bounds__(256) void fused_scan_kernel(
    const unsigned short* __restrict__ zxb, const float* __restrict__ dtraw,
    const float* __restrict__ cw, const float* __restrict__ cb,
    const float* __restrict__ dt_bias, const float* __restrict__ A_log,
    const float* __restrict__ D_skip,
    float* __restrict__ cumb, float* __restrict__ Dc,
    unsigned short* __restrict__ Cb, unsigned short* __restrict__ Sb,
    unsigned short* __restrict__ y){
  __shared__ __align__(16) unsigned short XshT[192*40];  /* X^T[p_local][t] */
  __shared__ __align__(16) unsigned short BshT[64*40];   /* B^T[n][t] */
  __shared__ __align__(16) unsigned short Bsh[32*72];    /* B[t][n] */
  __shared__ __align__(16) unsigned short Csh[32*72];    /* C[t][n] */
  __shared__ __align__(16) unsigned short Msh[2*32*40];  /* M~ per head */
  __shared__ float dtsh[64], Lsh[64], wsh[64];
  const int tid = threadIdx.x;
  const int bid = blockIdx.x;
  const int hp = bid & 3, c = (bid >> 2) & 31, b = bid >> 7;
  const int h_base = hp*2;
  const int t0 = c*CHUNK;

  if (tid < 64){
    int hi = tid >> 5, t = tid & 31;
    int hg = h_base + hi;
    float raw = dtraw[(size_t)(b*SEQ + t0 + t)*8 + hg];
    float dtv_ = softplus_f(raw + dt_bias[hg]);
    dtsh[tid] = dtv_;
    Lsh[tid]  = dtv_ * (-expf(A_log[hg]));
  }

  #pragma unroll
  for (int it=0; it<2; it++){
    int ci = it*256 + tid;
    if (ci < 320){
      int gcol;
      if (ci < 192) gcol = D_INNER + (h_base + ci/96)*HEADDIM + (ci%96);
      else          gcol = D_INNER + D_INNER + (ci - 192);
      int cch = gcol - D_INNER;
      float4 w4 = *(const float4*)(cw + cch*4);
      float bias = cb[cch];
      const unsigned short* src = zxb + (size_t)b*SEQ*ZXB_LD + gcol;
      float v0=0.f,v1=0.f,v2=0.f,v3=0.f;
      unsigned prev = 0;
      for (int t=-3; t<32; t++){
        int l = t0 + t;
        float nv = (l >= 0) ? bits_to_f(src[(size_t)l*ZXB_LD]) : 0.f;
        v0=v1; v1=v2; v2=v3; v3=nv;
        if (t < 0) continue;
        float a = silu_f(bias + w4.x*v0 + w4.y*v1 + w4.z*v2 + w4.w*v3);
        unsigned short ub = f_to_bits(a);
        if (ci < 192){
          if (t & 1) *(unsigned*)&XshT[ci*40 + (t-1)] = prev | ((unsigned)ub<<16);
          else prev = ub;
        } else if (cch < CONV_DIM - D_STATE){
          int n = cch - D_INNER;
          Bsh[t*72 + n] = ub;
          if (t & 1) *(unsigned*)&BshT[n*40 + (t-1)] = prev | ((unsigned)ub<<16);
          else prev = ub;
        } else {
          Csh[t*72 + (cch - D_INNER - D_STATE)] = ub;
        }
      }
    }
  }
  __syncthreads();

  if (tid < 2){
    int hg = h_base + tid;
    float L = 0.f;
    float* cbp = cumb + ((size_t)((b*NC + c)*NHEADS) + hg)*CHUNK;
    for (int t=0;t<32;t++){
      L += Lsh[tid*32+t];
      Lsh[tid*32+t] = L;
      cbp[t] = __expf(L);
    }
    Dc[(b*NHEADS + hg)*NC + c] = __expf(L);
    for (int t=0;t<32;t++)
      wsh[tid*32+t] = __expf(L - Lsh[tid*32+t]) * dtsh[tid*32+t];
  }
  __syncthreads();

  const int wave = tid >> 6, lane = tid & 63;
  const int lq = lane >> 4, lm = lane & 15;
  const f32x4_t zero = (f32x4_t){0.f,0.f,0.f,0.f};

  if (wave < 2){
    f32x4_t G[2][2];
    #pragma unroll
    for (int i=0;i<2;i++){ G[i][0]=zero; G[i][1]=zero; }
    #pragma unroll
    for (int kt=0; kt<2; kt++){
      bf16x8_t ca[2], bb[2];
      #pragma unroll
      for (int ti=0;ti<2;ti++)
        ca[ti] = *(const bf16x8_t*)&Csh[(lm+ti*16)*72 + kt*32 + lq*8];
      #pragma unroll
      for (int si=0;si<2;si++)
        bb[si] = *(const bf16x8_t*)&Bsh[(lm+si*16)*72 + kt*32 + lq*8];
      #pragma unroll
      for (int ti=0;ti<2;ti++)
        #pragma unroll
        for (int si=0;si<2;si++)
          G[ti][si] = __builtin_amdgcn_mfma_f32_16x16x32_bf16(ca[ti], bb[si], G[ti][si], 0,0,0);
    }
    int hi = wave;
    float Dk = D_skip[h_base + hi];
    float Lss[2], dts[2];
    #pragma unroll
    for (int si=0;si<2;si++){ Lss[si]=Lsh[hi*32+si*16+lm]; dts[si]=dtsh[hi*32+si*16+lm]; }
    #pragma unroll
    for (int ti=0;ti<2;ti++){
      #pragma unroll
      for (int r=0;r<4;r++){
        int t = ti*16 + lq*4 + r;
        float Lt = Lsh[hi*32 + t];
        #pragma unroll
        for (int si=0;si<2;si++){
          int s = si*16 + lm;
          float m = 0.f;
          if (s <= t){
            m = G[ti][si][r]*__expf(Lt - Lss[si])*dts[si];
            if (s == t) m += Dk;
          }
          Msh[hi*1280 + t*40 + s] = f_to_bits(m);
        }
      }
    }
  } else if (hp == 0){
    int lt = tid - 128;
    for (int i = lt; i < 512; i += 128){
      int t = i >> 4, q = i & 15;
      *(ushort4*)(Cb + ((size_t)(b*SEQ) + t0 + t)*D_STATE + q*4) =
          *(const ushort4*)&Csh[t*72 + q*4];
    }
  }
  __syncthreads();

  {
    int hi = wave & 1, hg = h_base + hi;
    int ptb = (wave >> 1)*3;
    bf16x8_t mf[2];
    #pragma unroll
    for (int tt=0;tt<2;tt++)
      mf[tt] = *(const bf16x8_t*)&Msh[hi*1280 + (lm+tt*16)*40 + lq*8];
    float wv[8];
    #pragma unroll
    for (int j=0;j<8;j++) wv[j] = wsh[hi*32 + lq*8 + j];
    bf16x8_t bw[4];
    #pragma unroll
    for (int nt=0;nt<4;nt++){
      bf16x8_t raw = *(const bf16x8_t*)&BshT[(lm+nt*16)*40 + lq*8];
      #pragma unroll
      for (int j=0;j<8;j++)
        bw[nt][j] = (short)f_to_bits(bits_to_f((unsigned short)raw[j]) * wv[j]);
    }
    const size_t sbase = ((size_t)((b*NC + c)*NHEADS) + hg)*HEADDIM*D_STATE;
    #pragma unroll
    for (int pp=0; pp<3; pp++){
      int pt = ptb + pp;
      bf16x8_t xf = *(const bf16x8_t*)&XshT[(hi*96 + pt*16 + lm)*40 + lq*8];
      #pragma unroll
      for (int tt=0;tt<2;tt++){
        f32x4_t a = __builtin_amdgcn_mfma_f32_16x16x32_bf16(mf[tt], xf, zero, 0,0,0);
        #pragma unroll
        for (int r=0;r<4;r++){
          int t = tt*16 + lq*4 + r;
          y[((size_t)(b*SEQ) + t0 + t)*D_INNER + hg*HEADDIM + pt*16 + lm] = f_to_bits(a[r]);
        }
      }
      #pragma unroll
      for (int nt=0;nt<4;nt++){
        f32x4_t s = __builtin_amdgcn_mfma_f32_16x16x32_bf16(xf, bw[nt], zero, 0,0,0);
        #pragma unroll
        for (int r=0;r<4;r++){
          int p = pt*16 + lq*4 + r;
          Sb[sbase + (size_t)p*D_STATE + nt*16 + lm] = f_to_bits(s[r]);
        }
      }
    }
  }
}

/* ---- sequential chunk combine on bf16 S (in-place -> Hin) --------------------- */
__global__ __launch_bounds__(256) void combine_kernel(
    unsigned short* __restrict__ S, const float* __restrict__ Dc){
  int g = blockIdx.x*256 + threadIdx.x;     /* (b,h,p,nq): 8*8*96*16 = 98304 */
  int nq = g & 15;
  int p  = (g >> 4) % 96;
  int h  = (g / (16*96)) & 7;
  int b  = g / (16*96*8);
  const float* Dp = Dc + (size_t)(b*NHEADS + h)*NC;
  float H0=0.f,H1=0.f,H2=0.f,H3=0.f;
  for (int c=0;c<NC;c++){
    size_t base = ((((size_t)(b*NC + c)*NHEADS + h)*HEADDIM + p)*D_STATE + nq*4);
    ushort4 s = *(ushort4*)(S + base);
    float s0=bits_to_f(s.x), s1=bits_to_f(s.y), s2=bits_to_f(s.z), s3=bits_to_f(s.w);
    *(ushort4*)(S + base) = make_ushort4(f_to_bits(H0),f_to_bits(H1),f_to_bits(H2),f_to_bits(H3));
    float D = Dp[c];
    H0 = fmaf(D,H0,s0); H1 = fmaf(D,H1,s1); H2 = fmaf(D,H2,s2); H3 = fmaf(D,H3,s3);
  }
}

/* ==== fused: y + cum*(C@Hin^T); gate silu(z); RMSNorm -> ygb (16-row blocks) === */
__global__ __launch_bounds__(256) void hinfuse_kernel(
    const unsigned short* __restrict__ Cb, const unsigned short* __restrict__ Hinb,
    const float* __restrict__ cumb, const unsigned short* __restrict__ zxb,
    const float* __restrict__ nw, const unsigned short* __restrict__ ybuf,
    unsigned short* __restrict__ ygb){
  __shared__ __align__(16) unsigned short Vsh[16*VP];
  __shared__ float cumsh[128];    /* [h][tl] for this 16-row half */
  __shared__ float rowsq[16];
  const int tid = threadIdx.x;
  const int half = blockIdx.x & 1;
  const int c = (blockIdx.x >> 1) & 31, b = blockIdx.x >> 6;
  const int t0 = c*CHUNK + half*16;
  if (tid < 128)
    cumsh[tid] = cumb[((size_t)((b*NC + c)*NHEADS) + (tid>>4))*CHUNK + half*16 + (tid&15)];
  if (tid < 16) rowsq[tid] = 0.f;
  __syncthreads();
  const int wave = tid >> 6, lane = tid & 63;
  const int lq = lane >> 4, lm = lane & 15;
  const f32x4_t zero = (f32x4_t){0.f,0.f,0.f,0.f};
  float sql[4] = {};
  for (int hh=0; hh<2; hh++){
    int h = wave*2 + hh;
    const unsigned short* Hb = Hinb + ((size_t)((b*NC + c)*NHEADS) + h)*HEADDIM*D_STATE;
    bf16x8_t ca[2];
    #pragma unroll
    for (int kt=0;kt<2;kt++)
      ca[kt] = *(const bf16x8_t*)(Cb +
          ((size_t)(b*SEQ) + t0 + lm)*D_STATE + kt*32 + lq*8);
    #pragma unroll
    for (int pt=0; pt<6; pt++){
      bf16x8_t hf0 = *(const bf16x8_t*)&Hb[(size_t)(lm+pt*16)*D_STATE + lq*8];
      bf16x8_t hf1 = *(const bf16x8_t*)&Hb[(size_t)(lm+pt*16)*D_STATE + 32 + lq*8];
      f32x4_t acc;
      acc = __builtin_amdgcn_mfma_f32_16x16x32_bf16(ca[0], hf0, zero, 0,0,0);
      acc = __builtin_amdgcn_mfma_f32_16x16x32_bf16(ca[1], hf1, acc, 0,0,0);
      int pcol = h*HEADDIM + pt*16 + lm;
      #pragma unroll
      for (int r=0;r<4;r++){
        int t = lq*4 + r;
        size_t row = (size_t)(b*SEQ) + t0 + t;
        float yv = bits_to_f(ybuf[row*D_INNER + pcol]) + cumsh[h*16+t]*acc[r];
        float z  = bits_to_f(zxb[row*ZXB_LD + pcol]);
        float v  = yv * silu_f(z);
        Vsh[t*VP + pcol] = f_to_bits(v);
        sql[r] += v*v;
      }
    }
  }
  #pragma unroll
  for (int r=0;r<4;r++){
    float v = sql[r];
    v += __shfl_xor(v,1); v += __shfl_xor(v,2);
    v += __shfl_xor(v,4); v += __shfl_xor(v,8);
    if (lm == 0) atomicAdd(&rowsq[lq*4 + r], v);
  }
  __syncthreads();
  if (tid < 16) rowsq[tid] = rsqrtf(rowsq[tid]*(1.f/D_INNER) + 1e-5f);
  __syncthreads();
  for (int i=tid; i<16*192; i+=256){
    int t = i/192, q = i%192;
    ushort4 pv = *(const ushort4*)&Vsh[t*VP + q*4];
    float rms = rowsq[t];
    float4 w4 = *(const float4*)(nw + q*4);
    ushort4 o;
    o.x = f_to_bits(bits_to_f(pv.x)*rms*w4.x);
    o.y = f_to_bits(bits_to_f(pv.y)*rms*w4.y);
    o.z = f_to_bits(bits_to_f(pv.z)*rms*w4.z);
    o.w = f_to_bits(bits_to_f(pv.w)*rms*w4.w);
    *(ushort4*)(ygb + ((size_t)(b*SEQ) + t0 + t)*D_INNER + q*4) = o;
  }
}

extern "C" void kernel_launch(void* const* d_in, const int* in_sizes, int n_in,
                              void* d_out, int out_size, void* d_ws, size_t ws_size,
                              hipStream_t stream){
  const float* x0      = (const float*)d_in[0];
  const float* ln_w    = (const float*)d_in[1];
  const float* ln_b    = (const float*)d_in[2];
  const float* W_in    = (const float*)d_in[3];
  const float* conv_w  = (const float*)d_in[4];
  const float* conv_b  = (const float*)d_in[5];
  const float* dt_bias = (const float*)d_in[6];
  const float* A_log   = (const float*)d_in[7];
  const float* D_skip  = (const float*)d_in[8];
  const float* norm_w  = (const float*)d_in[9];
  const float* W_out   = (const float*)d_in[10];
  float* out = (float*)d_out;

  float* p    = (float*)d_ws;
  unsigned short* zxb = (unsigned short*)p;   p += (size_t)ROWS*ZXB_LD/2;
  float* dtraw = p;  p += (size_t)ROWS*8;
  float* cumb  = p;  p += (size_t)BATCH*NHEADS*SEQ;
  float* Dc    = p;  p += (size_t)BATCH*NHEADS*NC;
  unsigned short* ybuf = (unsigned short*)p;  p += (size_t)ROWS*D_INNER/2;
  unsigned short* ygb  = (unsigned short*)p;  p += (size_t)ROWS*D_INNER/2;
  unsigned short* Sb   = (unsigned short*)p;  p += (size_t)BATCH*NC*NHEADS*HEADDIM*D_STATE/2;
  unsigned short* Cb   = (unsigned short*)p;  p += (size_t)ROWS*D_STATE/2;
  bf16* Wt  = (bf16*)p; p += (size_t)NUM_LAYERS*NPAD_IN*D_MODEL/2;
  bf16* Wot = (bf16*)p;
  bf16* hnb = (bf16*)Sb;   /* alias: live ln -> gemm_in, dead before fused_scan */

  hipMemcpyAsync(out, x0, (size_t)ROWS*D_MODEL*sizeof(float),
                 hipMemcpyDeviceToDevice, stream);

  wconv_kernel<<<dim3(NPAD_IN/32, D_MODEL/32, NUM_LAYERS), dim3(32,8), 0, stream>>>(
      W_in, Wt, D_MODEL, D_IN_PROJ, NPAD_IN);
  wconv_kernel<<<dim3(NPAD_OUT/32, D_INNER/32, NUM_LAYERS), dim3(32,8), 0, stream>>>(
      W_out, Wot, D_INNER, D_MODEL, NPAD_OUT);

  for (int i=0;i<NUM_LAYERS;i++){
    ln_kernel<<<ROWS,128,0,stream>>>(out, ln_w+(size_t)i*D_MODEL, ln_b+(size_t)i*D_MODEL, hnb);
    mfma_gemm<1><<<dim3(NPAD_IN/128, ROWS/128), 256, 0, stream>>>(
        (const unsigned short*)hnb, (const unsigned short*)(Wt + (size_t)i*NPAD_IN*D_MODEL),
        nullptr, zxb, dtraw, D_IN_PROJ, D_MODEL, 0);
    fused_scan_kernel<<<BATCH*NC*4, 256, 0, stream>>>(
        zxb, dtraw, conv_w + (size_t)i*CONV_DIM*4, conv_b + (size_t)i*CONV_DIM,
        dt_bias+(size_t)i*NHEADS, A_log+(size_t)i*NHEADS, D_skip+(size_t)i*NHEADS,
        cumb, Dc, Cb, Sb, ybuf);
    combine_kernel<<<(BATCH*NHEADS*HEADDIM*16)/256, 256, 0, stream>>>(Sb, Dc);
    hinfuse_kernel<<<BATCH*NC*2, 256, 0, stream>>>(
        Cb, Sb, cumb, zxb, norm_w+(size_t)i*D_INNER, ybuf, ygb);
    mfma_gemm<0><<<dim3(NPAD_OUT/128, ROWS/128), 256, 0, stream>>>(
        (const unsigned short*)ygb, (const unsigned short*)(Wot + (size_t)i*NPAD_OUT*D_INNER),
        out, nullptr, nullptr, D_MODEL, D_INNER, D_MODEL);
  }
}